// Round 5
// baseline (245.702 us; speedup 1.0000x reference)
//
#include <hip/hip_runtime.h>
#include <hip/hip_bf16.h>

// Problem constants
#define BB 512   // batch
#define SS 96    // seq len
#define NN 64    // nodes
#define HH 512   // hidden
#define EE 512   // edges per graph

typedef __attribute__((ext_vector_type(8))) short short8;   // 8 bf16 (4 VGPRs)
typedef __attribute__((ext_vector_type(4))) float f32x4;    // MFMA acc
typedef unsigned short u16;

__device__ __forceinline__ u16 f2bf(float f) {
    union { float f; unsigned u; } v; v.f = f;
    return (u16)((v.u + 0x7FFFu + ((v.u >> 16) & 1u)) >> 16);   // RNE
}
__device__ __forceinline__ short8 ld8bf(const u16* p) { return *(const short8*)p; }
// 8 consecutive fp32 -> bf16 A/B fragment (works for global or LDS pointers)
__device__ __forceinline__ short8 cvt8(const float* p) {
    float4 a = *(const float4*)p, b = *(const float4*)(p + 4);
    short8 r;
    r[0] = (short)f2bf(a.x); r[1] = (short)f2bf(a.y);
    r[2] = (short)f2bf(a.z); r[3] = (short)f2bf(a.w);
    r[4] = (short)f2bf(b.x); r[5] = (short)f2bf(b.y);
    r[6] = (short)f2bf(b.z); r[7] = (short)f2bf(b.w);
    return r;
}

// ---------------------------------------------------------------------------
// k_prep: one-time weight conversion to bf16 (removes per-block f32->bf16 VALU
// work and halves weight cache traffic). cw reordered (n,kw)->(kw,n).
// ---------------------------------------------------------------------------
__global__ __launch_bounds__(256) void k_prep(const float* __restrict__ W1,
                                              const float* __restrict__ W2,
                                              const float* __restrict__ cw,
                                              u16* __restrict__ W1b,
                                              u16* __restrict__ W2b,
                                              u16* __restrict__ Wcb) {
    const int i0 = blockIdx.x * 256 + threadIdx.x, stp = gridDim.x * 256;
    for (int i = i0; i < HH * SS; i += stp) W1b[i] = f2bf(W1[i]);
    for (int i = i0; i < SS * HH; i += stp) W2b[i] = f2bf(W2[i]);
    for (int i = i0; i < HH * 192; i += stp) {
        int h = i / 192, q = i % 192, n = q / 3, kw = q % 3;
        Wcb[h * 192 + kw * 64 + n] = f2bf(cw[i]);
    }
}

// ---------------------------------------------------------------------------
// k_AG: per graph: build normalized adjacency (LDS atomics), export Ab bf16,
// and G = A @ X^T via MFMA (B-frags converted directly from fp32 x).
// ---------------------------------------------------------------------------
__global__ __launch_bounds__(256) void k_AG(const float* __restrict__ x,
                                            const int* __restrict__ ei,
                                            u16* __restrict__ Ab,
                                            u16* __restrict__ G) {
    const int b = blockIdx.x, t = threadIdx.x;
    const int wave = t >> 6, lane = t & 63, quad = lane >> 4, l16 = lane & 15;
    __shared__ float Asm[4096];
    __shared__ int   deg[64];
    __shared__ float dinv[64];

    for (int i = t; i < 4096; i += 256) Asm[i] = 0.f;
    if (t < 64) deg[t] = 1;                       // self loop
    __syncthreads();
    const int* eb = ei + (size_t)b * 2 * EE;
    for (int e = t; e < EE; e += 256) atomicAdd(&deg[eb[EE + e]], 1);
    __syncthreads();
    if (t < 64) dinv[t] = rsqrtf((float)deg[t]);
    __syncthreads();
    for (int e = t; e < EE; e += 256) {
        int s = eb[e], d = eb[EE + e];
        atomicAdd(&Asm[d * 64 + s], dinv[s] * dinv[d]);
    }
    if (t < 64) atomicAdd(&Asm[t * 64 + t], dinv[t] * dinv[t]);
    __syncthreads();

    u16* Abb = Ab + (size_t)b * 4096;
    for (int i = t; i < 4096; i += 256) Abb[i] = f2bf(Asm[i]);

    // A-frags (rows n = wave*16+l16), kept in regs
    short8 af[2];
    af[0] = cvt8(&Asm[(wave * 16 + l16) * 64 + quad * 8]);
    af[1] = cvt8(&Asm[(wave * 16 + l16) * 64 + 32 + quad * 8]);

    const float* xb = x + (size_t)b * SS * NN;
    f32x4 acc[6];
    #pragma unroll
    for (int j = 0; j < 6; ++j) acc[j] = (f32x4){0.f, 0.f, 0.f, 0.f};
    #pragma unroll
    for (int j = 0; j < 6; ++j)
        #pragma unroll
        for (int kc = 0; kc < 2; ++kc) {
            short8 bb = cvt8(xb + (j * 16 + l16) * 64 + kc * 32 + quad * 8);
            acc[j] = __builtin_amdgcn_mfma_f32_16x16x32_bf16(af[kc], bb, acc[j], 0, 0, 0);
        }
    u16* Gb = G + (size_t)b * NN * SS;
    #pragma unroll
    for (int j = 0; j < 6; ++j)
        #pragma unroll
        for (int r = 0; r < 4; ++r)
            Gb[(wave * 16 + quad * 4 + r) * 96 + j * 16 + l16] = f2bf(acc[j][r]);
}

// ---------------------------------------------------------------------------
// k_h1: H1 = relu(G @ W1^T + b1), [32768,96]@[96,512]. LDS-free: every frag is
// one dwordx4 global load (bf16 rows, K contiguous); weights dedup via L1.
// Grid (4 h-tiles, 256 m-tiles); 4 waves 2x2, wave tile 64x64.
// ---------------------------------------------------------------------------
__global__ __launch_bounds__(256) void k_h1(const u16* __restrict__ G,
                                            const u16* __restrict__ W1b,
                                            const float* __restrict__ b1,
                                            u16* __restrict__ H1) {
    const int t = threadIdx.x;
    const int h0 = blockIdx.x * 128, m0 = blockIdx.y * 128;
    const int wave = t >> 6, lane = t & 63, quad = lane >> 4, l16 = lane & 15;
    const int wm = wave >> 1, wn = wave & 1;

    f32x4 acc[4][4];
    #pragma unroll
    for (int i = 0; i < 4; ++i)
        #pragma unroll
        for (int j = 0; j < 4; ++j) acc[i][j] = (f32x4){0.f, 0.f, 0.f, 0.f};

    #pragma unroll
    for (int kc = 0; kc < 3; ++kc) {
        short8 a[4], bf[4];
        #pragma unroll
        for (int i = 0; i < 4; ++i)
            a[i] = ld8bf(G + (size_t)(m0 + wm * 64 + i * 16 + l16) * 96 + kc * 32 + quad * 8);
        #pragma unroll
        for (int j = 0; j < 4; ++j)
            bf[j] = ld8bf(W1b + (size_t)(h0 + wn * 64 + j * 16 + l16) * 96 + kc * 32 + quad * 8);
        #pragma unroll
        for (int i = 0; i < 4; ++i)
            #pragma unroll
            for (int j = 0; j < 4; ++j)
                acc[i][j] = __builtin_amdgcn_mfma_f32_16x16x32_bf16(a[i], bf[j], acc[i][j], 0, 0, 0);
    }

    float bj[4];
    #pragma unroll
    for (int j = 0; j < 4; ++j) bj[j] = b1[h0 + wn * 64 + j * 16 + l16];

    #pragma unroll
    for (int i = 0; i < 4; ++i)
        #pragma unroll
        for (int j = 0; j < 4; ++j) {
            int h = h0 + wn * 64 + j * 16 + l16;
            #pragma unroll
            for (int r = 0; r < 4; ++r) {
                int m = m0 + wm * 64 + i * 16 + quad * 4 + r;
                H1[(size_t)m * HH + h] = f2bf(fmaxf(acc[i][j][r] + bj[j], 0.f));
            }
        }
}

// ---------------------------------------------------------------------------
// k_tT: Tt = W2 @ H1^T  ([96,512]@[512,32768] -> [96, 32768]).  LDS-free.
// Grid 512 (64-col tiles of m); 4 waves 2x2: wave = 48 s-rows x 32 m-cols.
// ---------------------------------------------------------------------------
__global__ __launch_bounds__(256) void k_tT(const u16* __restrict__ H1,
                                            const u16* __restrict__ W2b,
                                            u16* __restrict__ Tt) {
    const int t = threadIdx.x, m0 = blockIdx.x * 64;
    const int wave = t >> 6, lane = t & 63, quad = lane >> 4, l16 = lane & 15;
    const int wm = wave >> 1, wn = wave & 1;

    f32x4 acc[3][2];
    #pragma unroll
    for (int i = 0; i < 3; ++i)
        #pragma unroll
        for (int j = 0; j < 2; ++j) acc[i][j] = (f32x4){0.f, 0.f, 0.f, 0.f};

    for (int kc = 0; kc < 16; ++kc) {
        short8 a[3], bf[2];
        #pragma unroll
        for (int i = 0; i < 3; ++i)
            a[i] = ld8bf(W2b + (size_t)(wm * 48 + i * 16 + l16) * HH + kc * 32 + quad * 8);
        #pragma unroll
        for (int j = 0; j < 2; ++j)
            bf[j] = ld8bf(H1 + (size_t)(m0 + wn * 32 + j * 16 + l16) * HH + kc * 32 + quad * 8);
        #pragma unroll
        for (int i = 0; i < 3; ++i)
            #pragma unroll
            for (int j = 0; j < 2; ++j)
                acc[i][j] = __builtin_amdgcn_mfma_f32_16x16x32_bf16(a[i], bf[j], acc[i][j], 0, 0, 0);
    }

    #pragma unroll
    for (int i = 0; i < 3; ++i)
        #pragma unroll
        for (int j = 0; j < 2; ++j)
            #pragma unroll
            for (int r = 0; r < 4; ++r)
                Tt[(size_t)(wm * 48 + i * 16 + quad * 4 + r) * 32768
                   + m0 + wn * 32 + j * 16 + l16] = f2bf(acc[i][j][r]);
}

// ---------------------------------------------------------------------------
// k_h2: per graph: H2^T = Tt_slice @ A^T + b2  -> H2T [96 s][64 n] bf16.
// LDS-free; wave w owns n-columns w*16..w*16+15.
// ---------------------------------------------------------------------------
__global__ __launch_bounds__(256) void k_h2(const u16* __restrict__ Tt,
                                            const u16* __restrict__ Ab,
                                            const float* __restrict__ b2,
                                            u16* __restrict__ H2T) {
    const int b = blockIdx.x, t = threadIdx.x;
    const int wave = t >> 6, lane = t & 63, quad = lane >> 4, l16 = lane & 15;

    short8 bf[2];   // B = adjacency rows n = wave*16+l16, k = m
    #pragma unroll
    for (int kc = 0; kc < 2; ++kc)
        bf[kc] = ld8bf(Ab + (size_t)b * 4096 + (wave * 16 + l16) * 64 + kc * 32 + quad * 8);

    f32x4 acc[6];
    #pragma unroll
    for (int i = 0; i < 6; ++i) acc[i] = (f32x4){0.f, 0.f, 0.f, 0.f};
    #pragma unroll
    for (int i = 0; i < 6; ++i)
        #pragma unroll
        for (int kc = 0; kc < 2; ++kc) {
            short8 aa = ld8bf(Tt + (size_t)(i * 16 + l16) * 32768 + b * 64 + kc * 32 + quad * 8);
            acc[i] = __builtin_amdgcn_mfma_f32_16x16x32_bf16(aa, bf[kc], acc[i], 0, 0, 0);
        }

    u16* Hb = H2T + (size_t)b * SS * NN;
    #pragma unroll
    for (int i = 0; i < 6; ++i)
        #pragma unroll
        for (int r = 0; r < 4; ++r) {
            int s = i * 16 + quad * 4 + r;
            Hb[s * 64 + wave * 16 + l16] = f2bf(acc[i][r] + b2[s]);
        }
}

// ---------------------------------------------------------------------------
// k_conv: y[s][h] = sum_{kw,n} Wcb[h][kw*64+n] * H2T[(s+kw-1)%96][n].
// LDS-free: A-frags (weights) held in regs, B-frags one dwordx4 each (L1-hot:
// the 12 KB H2T tile and 24.6 KB weight tile both fit L1). float4 stores.
// ---------------------------------------------------------------------------
__global__ __launch_bounds__(256) void k_conv(const u16* __restrict__ H2T,
                                              const u16* __restrict__ Wcb,
                                              float* __restrict__ out) {
    const int hb = blockIdx.x, b = blockIdx.y, t = threadIdx.x;
    const int wave = t >> 6, lane = t & 63, quad = lane >> 4, l16 = lane & 15;
    const int h0 = hb * 64;

    short8 a[6];
    #pragma unroll
    for (int kc = 0; kc < 6; ++kc)
        a[kc] = ld8bf(Wcb + (size_t)(h0 + wave * 16 + l16) * 192 + kc * 32 + quad * 8);

    const u16* Hg = H2T + (size_t)b * SS * NN;
    float* ob = out + (size_t)b * SS * HH;

    #pragma unroll
    for (int j = 0; j < 6; ++j) {
        f32x4 acc = (f32x4){0.f, 0.f, 0.f, 0.f};
        #pragma unroll
        for (int kc = 0; kc < 6; ++kc) {
            int kw = kc >> 1, nb = (kc & 1) * 32;
            int s2 = j * 16 + l16 + kw - 1;          // -1..96
            s2 = (s2 < 0) ? 95 : ((s2 > 95) ? 0 : s2);
            short8 bf = ld8bf(Hg + s2 * 64 + nb + quad * 8);
            acc = __builtin_amdgcn_mfma_f32_16x16x32_bf16(a[kc], bf, acc, 0, 0, 0);
        }
        float4 vv = {acc[0], acc[1], acc[2], acc[3]};
        *(float4*)(ob + (size_t)(j * 16 + l16) * HH + h0 + wave * 16 + quad * 4) = vv;
    }
}

// ---------------------------------------------------------------------------
extern "C" void kernel_launch(void* const* d_in, const int* in_sizes, int n_in,
                              void* d_out, int out_size, void* d_ws, size_t ws_size,
                              hipStream_t stream) {
    const float* x  = (const float*)d_in[0];
    const int*   ei = (const int*)d_in[1];
    const float* W1 = (const float*)d_in[2];
    const float* b1 = (const float*)d_in[3];
    const float* W2 = (const float*)d_in[4];
    const float* b2 = (const float*)d_in[5];
    const float* cw = (const float*)d_in[6];
    float* out = (float*)d_out;

    char* w = (char*)d_ws;
    u16* Ab  = (u16*)w;                       // 512*4096*2   = 4,194,304
    u16* G   = (u16*)(w + 4194304);           // 32768*96*2   = 6,291,456
    u16* Tt  = G;                             // overlay: G dead after k_h1
    u16* H2T = (u16*)(w + 10485760);          // 512*96*64*2  = 6,291,456
    u16* W1b = (u16*)(w + 16777216);          // 98,304
    u16* W2b = (u16*)(w + 16875520);          // 98,304
    u16* Wcb = (u16*)(w + 16973824);          // 196,608  (total ws 16.4 MiB)
    u16* H1  = (u16*)d_out;                   // 33.5 MB scratch inside 100 MB out

    k_prep<<<192, 256, 0, stream>>>(W1, W2, cw, W1b, W2b, Wcb);
    k_AG  <<<BB, 256, 0, stream>>>(x, ei, Ab, G);
    dim3 g1(4, 256);
    k_h1  <<<g1, 256, 0, stream>>>(G, W1b, b1, H1);
    k_tT  <<<BB, 256, 0, stream>>>(H1, W2b, Tt);
    k_h2  <<<BB, 256, 0, stream>>>(Tt, Ab, b2, H2T);
    dim3 gc(8, BB);
    k_conv<<<gc, 256, 0, stream>>>(H2T, Wcb, out);
}

// Round 6
// 172.789 us; speedup vs baseline: 1.4220x; 1.4220x over previous
//
#include <hip/hip_runtime.h>
#include <hip/hip_bf16.h>

// Problem constants
#define BB 512   // batch
#define SS 96    // seq len
#define NN 64    // nodes
#define HH 512   // hidden
#define EE 512   // edges per graph

typedef __attribute__((ext_vector_type(8))) short short8;   // 8 bf16 (4 VGPRs)
typedef __attribute__((ext_vector_type(4))) float f32x4;    // MFMA acc
typedef unsigned short u16;

__device__ __forceinline__ u16 f2bf(float f) {
    union { float f; unsigned u; } v; v.f = f;
    return (u16)((v.u + 0x7FFFu + ((v.u >> 16) & 1u)) >> 16);   // RNE
}
__device__ __forceinline__ short8 ld8bf(const u16* p) { return *(const short8*)p; }
__device__ __forceinline__ short8 cvt8(const float* p) {       // 8 fp32 -> bf16 frag
    float4 a = *(const float4*)p, b = *(const float4*)(p + 4);
    short8 r;
    r[0] = (short)f2bf(a.x); r[1] = (short)f2bf(a.y);
    r[2] = (short)f2bf(a.z); r[3] = (short)f2bf(a.w);
    r[4] = (short)f2bf(b.x); r[5] = (short)f2bf(b.y);
    r[6] = (short)f2bf(b.z); r[7] = (short)f2bf(b.w);
    return r;
}
__device__ __forceinline__ ushort4 packbf(f32x4 a) {
    ushort4 u; u.x = f2bf(a[0]); u.y = f2bf(a[1]); u.z = f2bf(a[2]); u.w = f2bf(a[3]);
    return u;
}

// ---------------------------------------------------------------------------
// k_prep: weights -> bf16; conv weight reordered (n,kw) -> (kw,n).
// ---------------------------------------------------------------------------
__global__ __launch_bounds__(256) void k_prep(const float* __restrict__ W1,
                                              const float* __restrict__ W2,
                                              const float* __restrict__ cw,
                                              u16* __restrict__ W1b,
                                              u16* __restrict__ W2b,
                                              u16* __restrict__ Wcb) {
    const int i0 = blockIdx.x * 256 + threadIdx.x, stp = gridDim.x * 256;
    for (int i = i0; i < HH * SS; i += stp) W1b[i] = f2bf(W1[i]);
    for (int i = i0; i < SS * HH; i += stp) W2b[i] = f2bf(W2[i]);
    for (int i = i0; i < HH * 192; i += stp) {
        int h = i / 192, q = i % 192, n = q / 3, kw = q % 3;
        Wcb[h * 192 + kw * 64 + n] = f2bf(cw[i]);
    }
}

// ---------------------------------------------------------------------------
// k_all: one block per graph; the entire model, LDS-resident.
//   phase0: adjacency Asm (f32, LDS atomics) -> As bf16 [64 n][72]
//   MFMA0 : C[s][node] = X @ A^T      (A-op = x rows s, B-op = As rows node)
//           -> Gs[node][s]  (b64 packed writes; rows wave-private)
//   chunk loop hc=0..7 (BARRIER-FREE: H1c rows wave-private):
//     MFMA1: C[h][node] = W1c @ G^T   -> H1c[node][h] (+bias, relu, b64)
//     MFMA2: C[node][s] accT += H1c @ W2c^T   (regs)
//   Ts[s][m] <- accT (b64), barrier
//   MFMA3 : C[n][s] = A @ T (A-op = As rows n, B-op = Ts rows s)
//           -> Hp[s+1][n] (+b2, b64), barrier, circular pad
//   conv  : 8 h-tiles: C[h][s] = Wc @ Hp-shift; float4 stores (no barriers)
// LDS map (59680 B): As@0(9216) Gs@9216(13312) H1c@22528(9216)
//   Ts@31744(13824) Hp@45568(14112); Asm f32[4096]@31744 (dead before Ts/Hp);
//   deg@0,dinv@256 (dead before As).
// ---------------------------------------------------------------------------
__global__ __launch_bounds__(256) void k_all(const float* __restrict__ x,
                                             const int* __restrict__ ei,
                                             const u16* __restrict__ W1b,
                                             const float* __restrict__ b1,
                                             const u16* __restrict__ W2b,
                                             const float* __restrict__ b2,
                                             const u16* __restrict__ Wcb,
                                             float* __restrict__ out) {
    const int b = blockIdx.x, t = threadIdx.x;
    const int w = t >> 6, lane = t & 63, quad = lane >> 4, l16 = lane & 15;

    __shared__ __align__(16) char smem[59680];
    u16*   As   = (u16*)smem;
    u16*   Gs   = (u16*)(smem + 9216);
    u16*   H1c  = (u16*)(smem + 22528);
    u16*   Ts   = (u16*)(smem + 31744);
    u16*   Hp   = (u16*)(smem + 45568);
    float* Asm  = (float*)(smem + 31744);
    int*   deg  = (int*)smem;
    float* dinv = (float*)(smem + 256);

    // ---- phase 0: normalized adjacency ----
    for (int i = t; i < 4096; i += 256) Asm[i] = 0.f;
    if (t < 64) deg[t] = 1;                         // self loop
    __syncthreads();
    const int* eb = ei + (size_t)b * 2 * EE;
    for (int e = t; e < EE; e += 256) atomicAdd(&deg[eb[EE + e]], 1);
    __syncthreads();
    if (t < 64) dinv[t] = rsqrtf((float)deg[t]);
    __syncthreads();
    for (int e = t; e < EE; e += 256) {
        int s = eb[e], d = eb[EE + e];
        atomicAdd(&Asm[d * 64 + s], dinv[s] * dinv[d]);
    }
    if (t < 64) atomicAdd(&Asm[t * 64 + t], dinv[t] * dinv[t]);
    __syncthreads();
    // As bf16 [64][72] (overwrites deg/dinv - dead)
    for (int i = t; i < 1024; i += 256) {
        int n = i >> 4, m4 = (i & 15) * 4;
        f32x4 v = *(const f32x4*)(Asm + n * 64 + m4);
        *(ushort4*)(As + n * 72 + m4) = packbf(v);
    }
    __syncthreads();

    // ---- MFMA0: Gs[node][s] ----
    {
        short8 bf0[2];
        #pragma unroll
        for (int kc = 0; kc < 2; ++kc)
            bf0[kc] = ld8bf(As + (w * 16 + l16) * 72 + kc * 32 + quad * 8);
        const float* xb = x + (size_t)b * SS * NN;
        #pragma unroll
        for (int j = 0; j < 6; ++j) {
            f32x4 acc = (f32x4){0.f, 0.f, 0.f, 0.f};
            #pragma unroll
            for (int kc = 0; kc < 2; ++kc) {
                short8 a = cvt8(xb + (j * 16 + l16) * 64 + kc * 32 + quad * 8);
                acc = __builtin_amdgcn_mfma_f32_16x16x32_bf16(a, bf0[kc], acc, 0, 0, 0);
            }
            // col=l16 -> node=w*16+l16 ; row=quad*4+r -> s=j*16+quad*4+r
            *(ushort4*)(Gs + (w * 16 + l16) * 104 + j * 16 + quad * 4) = packbf(acc);
        }
    }
    // Gs/H1c rows are wave-private: no barrier needed through the chunk loop.

    // ---- hidden-chunk loop (barrier-free) ----
    f32x4 accT[6];
    #pragma unroll
    for (int j = 0; j < 6; ++j) accT[j] = (f32x4){0.f, 0.f, 0.f, 0.f};

    for (int hc = 0; hc < 8; ++hc) {
        short8 gb[3];
        #pragma unroll
        for (int kc = 0; kc < 3; ++kc)
            gb[kc] = ld8bf(Gs + (w * 16 + l16) * 104 + kc * 32 + quad * 8);
        // MFMA1: C[h][node] -> H1c[node][h]
        #pragma unroll
        for (int hs = 0; hs < 4; ++hs) {
            f32x4 a1 = (f32x4){0.f, 0.f, 0.f, 0.f};
            #pragma unroll
            for (int kc = 0; kc < 3; ++kc) {
                short8 wa = ld8bf(W1b + (size_t)(hc * 64 + hs * 16 + l16) * 96 + kc * 32 + quad * 8);
                a1 = __builtin_amdgcn_mfma_f32_16x16x32_bf16(wa, gb[kc], a1, 0, 0, 0);
            }
            float4 bias = *(const float4*)(b1 + hc * 64 + hs * 16 + quad * 4);
            f32x4 r;
            r[0] = fmaxf(a1[0] + bias.x, 0.f); r[1] = fmaxf(a1[1] + bias.y, 0.f);
            r[2] = fmaxf(a1[2] + bias.z, 0.f); r[3] = fmaxf(a1[3] + bias.w, 0.f);
            *(ushort4*)(H1c + (w * 16 + l16) * 72 + hs * 16 + quad * 4) = packbf(r);
        }
        // MFMA2: accT[node][s] += H1c @ W2c^T
        short8 ha[2];
        #pragma unroll
        for (int kc = 0; kc < 2; ++kc)
            ha[kc] = ld8bf(H1c + (w * 16 + l16) * 72 + kc * 32 + quad * 8);
        #pragma unroll
        for (int j = 0; j < 6; ++j)
            #pragma unroll
            for (int kc = 0; kc < 2; ++kc) {
                short8 wb = ld8bf(W2b + (size_t)(j * 16 + l16) * HH + hc * 64 + kc * 32 + quad * 8);
                accT[j] = __builtin_amdgcn_mfma_f32_16x16x32_bf16(ha[kc], wb, accT[j], 0, 0, 0);
            }
    }

    // ---- Ts[s][m] <- accT ----
    #pragma unroll
    for (int j = 0; j < 6; ++j)   // col=l16 -> s=j*16+l16 ; rows node=w*16+quad*4+r
        *(ushort4*)(Ts + (j * 16 + l16) * 72 + w * 16 + quad * 4) = packbf(accT[j]);
    __syncthreads();

    // ---- MFMA3: Hp[s+1][n] = A @ T + b2 ----
    {
        short8 af[2];
        #pragma unroll
        for (int kc = 0; kc < 2; ++kc)
            af[kc] = ld8bf(As + (w * 16 + l16) * 72 + kc * 32 + quad * 8);
        #pragma unroll
        for (int j = 0; j < 6; ++j) {
            f32x4 a3 = (f32x4){0.f, 0.f, 0.f, 0.f};
            #pragma unroll
            for (int kc = 0; kc < 2; ++kc) {
                short8 tb = ld8bf(Ts + (j * 16 + l16) * 72 + kc * 32 + quad * 8);
                a3 = __builtin_amdgcn_mfma_f32_16x16x32_bf16(af[kc], tb, a3, 0, 0, 0);
            }
            float bs = b2[j * 16 + l16];
            f32x4 r = {a3[0] + bs, a3[1] + bs, a3[2] + bs, a3[3] + bs};
            // col=l16 -> s=j*16+l16 ; rows n=w*16+quad*4+r
            *(ushort4*)(Hp + (j * 16 + l16 + 1) * 72 + w * 16 + quad * 4) = packbf(r);
        }
    }
    __syncthreads();
    if (t < 64) {                      // circular pad rows
        Hp[t] = Hp[96 * 72 + t];       // sp=0  <- s=95
        Hp[97 * 72 + t] = Hp[72 + t];  // sp=97 <- s=0
    }
    __syncthreads();

    // ---- conv: 8 h-tiles, no barriers ----
    float* ob = out + (size_t)b * SS * HH;
    for (int ht = 0; ht < 8; ++ht) {
        short8 wa[6];
        #pragma unroll
        for (int kc = 0; kc < 6; ++kc)
            wa[kc] = ld8bf(Wcb + (size_t)(ht * 64 + w * 16 + l16) * 192 + kc * 32 + quad * 8);
        #pragma unroll
        for (int j = 0; j < 6; ++j) {
            f32x4 acc = (f32x4){0.f, 0.f, 0.f, 0.f};
            #pragma unroll
            for (int kc = 0; kc < 6; ++kc) {
                int kw = kc >> 1, nb = (kc & 1) * 32;
                short8 hb = ld8bf(Hp + (j * 16 + l16 + kw) * 72 + nb + quad * 8);
                acc = __builtin_amdgcn_mfma_f32_16x16x32_bf16(wa[kc], hb, acc, 0, 0, 0);
            }
            // col=l16 -> s=j*16+l16 ; rows h=ht*64+w*16+quad*4+r (float4, 64B/row)
            float4 vv = {acc[0], acc[1], acc[2], acc[3]};
            *(float4*)(ob + (size_t)(j * 16 + l16) * HH + ht * 64 + w * 16 + quad * 4) = vv;
        }
    }
}

// ---------------------------------------------------------------------------
extern "C" void kernel_launch(void* const* d_in, const int* in_sizes, int n_in,
                              void* d_out, int out_size, void* d_ws, size_t ws_size,
                              hipStream_t stream) {
    const float* x  = (const float*)d_in[0];
    const int*   ei = (const int*)d_in[1];
    const float* W1 = (const float*)d_in[2];
    const float* b1 = (const float*)d_in[3];
    const float* W2 = (const float*)d_in[4];
    const float* b2 = (const float*)d_in[5];
    const float* cw = (const float*)d_in[6];
    float* out = (float*)d_out;

    char* wsp = (char*)d_ws;                 // total 384 KiB of workspace
    u16* W1b = (u16*)wsp;                    // 98,304 B
    u16* W2b = (u16*)(wsp + 98304);          // 98,304 B
    u16* Wcb = (u16*)(wsp + 196608);         // 196,608 B

    k_prep<<<96, 256, 0, stream>>>(W1, W2, cw, W1b, W2b, Wcb);
    k_all <<<BB, 256, 0, stream>>>(x, ei, W1b, b1, W2b, b2, Wcb, out);
}